// Round 1
// baseline (1010.121 us; speedup 1.0000x reference)
//
#include <hip/hip_runtime.h>
#include <math.h>

#define BN  32
#define H   80
#define W   80
#define HW  6400
#define KC  100
#define NCH 90
#define UW  640
#define UHW 409600   // 640*640

static constexpr size_t OUT_MNT   = 0;
static constexpr size_t OUT_KEEP  = (size_t)BN * KC * 4;          // 12800
static constexpr size_t OUT_ENH   = OUT_KEEP + (size_t)BN * KC;   // 16000
static constexpr size_t OUT_CLEAN = OUT_ENH + (size_t)BN * UHW;   // 13123200
static constexpr size_t OUT_ORI   = OUT_CLEAN + (size_t)BN * UHW; // 26230400

#define PI_F 3.14159265358979323846

// ---------------- Kernel 1: cleaned mask (round -> blur5x5 -> round) ---------
__global__ __launch_bounds__(256) void k_cleaned(const float* __restrict__ seg,
                                                 float* __restrict__ cleaned) {
    int t = blockIdx.x * 256 + threadIdx.x;
    if (t >= BN * HW) return;
    int b = t / HW, p = t % HW;
    int h = p / W, w = p % W;

    // gaussian weights, float32 math like the reference
    float g[5];
    {
        float s = 0.f;
        #pragma unroll
        for (int i = 0; i < 5; i++) {
            float c = (float)(i - 2);
            g[i] = expf(-(c * c) / 4.5f);
            s += g[i];
        }
        #pragma unroll
        for (int i = 0; i < 5; i++) g[i] /= s;
    }

    const float* sb = seg + (size_t)b * HW;
    float acc = 0.f;
    #pragma unroll
    for (int dy = -2; dy <= 2; dy++) {
        int hh = h + dy;
        if (hh < 0 || hh >= H) continue;
        float rowacc = 0.f;
        #pragma unroll
        for (int dx = -2; dx <= 2; dx++) {
            int ww = w + dx;
            if (ww < 0 || ww >= W) continue;
            rowacc += rintf(sb[hh * W + ww]) * g[dx + 2];
        }
        acc += rowacc * g[dy + 2];
    }
    cleaned[t] = rintf(acc);
}

// ---------------- Kernel 2: per-batch top-K + detect + sequential NMS --------
__global__ __launch_bounds__(256) void k_detect(const float* __restrict__ mscore,
                                                const float* __restrict__ mori,
                                                const float* __restrict__ mxo,
                                                const float* __restrict__ myo,
                                                const float* __restrict__ cleaned,
                                                float* __restrict__ out) {
    __shared__ float s_score[HW];
    __shared__ float s_rv[256];
    __shared__ int   s_ri[256];
    __shared__ float s_x[KC], s_y[KC], s_ang[KC], s_val[KC];
    __shared__ int   s_idx[KC];
    __shared__ int   s_keep[KC];

    const int b = blockIdx.x, tid = threadIdx.x;

    for (int i = tid; i < HW; i += 256)
        s_score[i] = mscore[(size_t)b * HW + i] * cleaned[(size_t)b * HW + i];
    __syncthreads();

    // iterative top-K: (value desc, index asc)
    for (int k = 0; k < KC; k++) {
        float bv = -2.f; int bi = 0x7fffffff;
        for (int i = tid; i < HW; i += 256) {
            float v = s_score[i];
            if (v > bv) { bv = v; bi = i; }   // ascending i keeps smallest idx
        }
        s_rv[tid] = bv; s_ri[tid] = bi;
        __syncthreads();
        for (int off = 128; off > 0; off >>= 1) {
            if (tid < off) {
                float ov = s_rv[tid + off]; int oi = s_ri[tid + off];
                if (ov > s_rv[tid] || (ov == s_rv[tid] && oi < s_ri[tid])) {
                    s_rv[tid] = ov; s_ri[tid] = oi;
                }
            }
            __syncthreads();
        }
        if (tid == 0) {
            s_val[k] = s_rv[0];
            s_idx[k] = s_ri[0];
            s_score[s_ri[0]] = -1.f;  // remove (scores >= 0)
        }
        __syncthreads();
    }

    // per-candidate channel argmaxes + mnt
    if (tid < KC) {
        int idx = s_idx[tid];
        int r = idx / W, c = idx % W;

        const float* pm = mori + (size_t)b * NCH * HW + idx;
        float best = pm[0]; int bj = 0;
        for (int j = 1; j < NCH; j++) {
            float v = pm[(size_t)j * HW];
            if (v > best) { best = v; bj = j; }
        }
        const float* px = mxo + (size_t)b * 8 * HW + idx;
        float bxv = px[0]; int xo = 0;
        #pragma unroll
        for (int j = 1; j < 8; j++) { float v = px[(size_t)j * HW]; if (v > bxv) { bxv = v; xo = j; } }
        const float* py = myo + (size_t)b * 8 * HW + idx;
        float byv = py[0]; int yo = 0;
        #pragma unroll
        for (int j = 1; j < 8; j++) { float v = py[(size_t)j * HW]; if (v > byv) { byv = v; yo = j; } }

        float ang = ((float)bj * 2.0f - 89.0f) * (float)(PI_F / 180.0);
        float x = (float)c * 8.0f + (float)xo;
        float y = (float)r * 8.0f + (float)yo;
        s_x[tid] = x; s_y[tid] = y; s_ang[tid] = ang;
        s_keep[tid] = (s_val[tid] > 0.1f) ? 1 : 0;

        float* m = out + OUT_MNT + ((size_t)b * KC + tid) * 4;
        m[0] = x; m[1] = y; m[2] = ang; m[3] = s_val[tid];
    }
    __syncthreads();

    // sequential NMS
    for (int i = 0; i < KC; i++) {
        if (s_keep[i]) {
            if (tid < KC && tid > i && s_keep[tid]) {
                float dx = s_x[i] - s_x[tid];
                float dy = s_y[i] - s_y[tid];
                float dist = sqrtf(dx * dx + dy * dy);
                float ad = fabsf(s_ang[i] - s_ang[tid]);
                float am = fminf(ad, 2.0f * (float)PI_F - ad);
                if (dist < 16.0f && am < (float)(PI_F / 6.0)) s_keep[tid] = 0;
            }
        }
        __syncthreads();
    }

    if (tid < KC)
        out[OUT_KEEP + (size_t)b * KC + tid] = s_keep[tid] ? 1.0f : 0.0f;
}

// ---------------- Kernel 3: orientation argmax over 90 channels --------------
__global__ __launch_bounds__(256) void k_ori(const float* __restrict__ ori,
                                             float* __restrict__ ori_idx) {
    int t = blockIdx.x * 256 + threadIdx.x;
    if (t >= BN * HW) return;
    int b = t / HW, p = t % HW;
    const float* o = ori + (size_t)b * NCH * HW + p;
    float best = o[0]; int bj = 0;
    for (int j = 1; j < NCH; j++) {
        float v = o[(size_t)j * HW];
        if (v > best) { best = v; bj = j; }
    }
    ori_idx[t] = (float)bj;
}

// ---------------- min/max encoding ----------------
__device__ __forceinline__ unsigned enc_f(float f) {
    unsigned u = __float_as_uint(f);
    return (u & 0x80000000u) ? ~u : (u | 0x80000000u);
}
__device__ __forceinline__ float dec_f(unsigned k) {
    return (k & 0x80000000u) ? __uint_as_float(k ^ 0x80000000u) : __uint_as_float(~k);
}

__global__ void k_mm_init(unsigned* __restrict__ mm) {
    int t = threadIdx.x;
    if (t < BN) { mm[2 * t] = 0xFFFFFFFFu; mm[2 * t + 1] = 0u; }
}

// ---------------- Kernel 4: per-image min/max of enhanced*mask ---------------
__global__ __launch_bounds__(256) void k_minmax(const float* __restrict__ enh,
                                                const float* __restrict__ cleaned,
                                                unsigned* __restrict__ mm) {
    int t = blockIdx.x * 256 + threadIdx.x;   // exactly BN*UHW threads
    int b = t / UHW, p = t % UHW;
    int Y = p / UW, X = p % UW;
    float c = cleaned[(size_t)b * HW + (Y >> 3) * W + (X >> 3)];
    unsigned key = enc_f(enh[t] * c);

    __shared__ unsigned smin[256], smax[256];
    smin[threadIdx.x] = key; smax[threadIdx.x] = key;
    __syncthreads();
    for (int off = 128; off > 0; off >>= 1) {
        if (threadIdx.x < off) {
            smin[threadIdx.x] = min(smin[threadIdx.x], smin[threadIdx.x + off]);
            smax[threadIdx.x] = max(smax[threadIdx.x], smax[threadIdx.x + off]);
        }
        __syncthreads();
    }
    if (threadIdx.x == 0) {
        atomicMin(&mm[2 * b], smin[0]);
        atomicMax(&mm[2 * b + 1], smax[0]);
    }
}

// ---------------- Kernel 5: fused upsample + normalize + writes --------------
__global__ __launch_bounds__(256) void k_final(const float* __restrict__ enh,
                                               const float* __restrict__ cleaned,
                                               const float* __restrict__ ori_idx,
                                               const unsigned* __restrict__ mm,
                                               float* __restrict__ out) {
    int t = blockIdx.x * 256 + threadIdx.x;   // exactly BN*UHW threads
    int b = t / UHW, p = t % UHW;
    int Y = p / UW, X = p % UW;
    int cidx = b * HW + (Y >> 3) * W + (X >> 3);
    float c  = cleaned[cidx];
    float oi = ori_idx[cidx];
    float e  = enh[t];
    float emin = dec_f(mm[2 * b]);
    float emax = dec_f(mm[2 * b + 1]);

    float ev = (e * c - emin) / (emax - emin + 1e-8f) * 255.0f;
    out[OUT_ENH   + t] = ev;
    out[OUT_CLEAN + t] = c * 255.0f;
    out[OUT_ORI   + t] = (oi * 2.0f - 89.0f) * (float)(PI_F / 180.0) * c;
}

extern "C" void kernel_launch(void* const* d_in, const int* in_sizes, int n_in,
                              void* d_out, int out_size, void* d_ws, size_t ws_size,
                              hipStream_t stream) {
    const float* seg    = (const float*)d_in[0];
    const float* mscore = (const float*)d_in[1];
    const float* mori   = (const float*)d_in[2];
    const float* mxo    = (const float*)d_in[3];
    const float* myo    = (const float*)d_in[4];
    const float* ori    = (const float*)d_in[5];
    const float* enh    = (const float*)d_in[6];
    float* out = (float*)d_out;

    // workspace layout
    float*    cleaned = (float*)d_ws;                       // BN*HW floats
    float*    ori_idx = cleaned + (size_t)BN * HW;          // BN*HW floats
    unsigned* mm      = (unsigned*)(ori_idx + (size_t)BN * HW); // 2*BN uints

    const int nSmall = (BN * HW + 255) / 256;   // 800
    const int nBig   = (BN * UHW) / 256;        // 51200

    k_cleaned<<<nSmall, 256, 0, stream>>>(seg, cleaned);
    k_mm_init<<<1, 64, 0, stream>>>(mm);
    k_detect<<<BN, 256, 0, stream>>>(mscore, mori, mxo, myo, cleaned, out);
    k_ori<<<nSmall, 256, 0, stream>>>(ori, ori_idx);
    k_minmax<<<nBig, 256, 0, stream>>>(enh, cleaned, mm);
    k_final<<<nBig, 256, 0, stream>>>(enh, cleaned, ori_idx, mm, out);
}

// Round 2
// 226.622 us; speedup vs baseline: 4.4573x; 4.4573x over previous
//
#include <hip/hip_runtime.h>
#include <math.h>

#define BN  32
#define H   80
#define W   80
#define HW  6400
#define KC  100
#define NCH 90
#define UW  640
#define UHW 409600   // 640*640

static constexpr size_t OUT_MNT   = 0;
static constexpr size_t OUT_KEEP  = (size_t)BN * KC * 4;          // 12800
static constexpr size_t OUT_ENH   = OUT_KEEP + (size_t)BN * KC;   // 16000
static constexpr size_t OUT_CLEAN = OUT_ENH + (size_t)BN * UHW;   // 13123200
static constexpr size_t OUT_ORI   = OUT_CLEAN + (size_t)BN * UHW; // 26230400

#define PI_F 3.14159265358979323846
#define MM_BLOCKS 64   // partial-reduction blocks per batch image

// ---------------- float <-> order-preserving uint ----------------
__device__ __forceinline__ unsigned enc_f(float f) {
    unsigned u = __float_as_uint(f);
    return (u & 0x80000000u) ? ~u : (u | 0x80000000u);
}
__device__ __forceinline__ float dec_f(unsigned k) {
    return (k & 0x80000000u) ? __uint_as_float(k ^ 0x80000000u) : __uint_as_float(~k);
}

// ---------------- Kernel 1: cleaned mask (round -> blur5x5 -> round) ---------
__global__ __launch_bounds__(256) void k_cleaned(const float* __restrict__ seg,
                                                 float* __restrict__ cleaned) {
    int t = blockIdx.x * 256 + threadIdx.x;
    if (t >= BN * HW) return;
    int b = t / HW, p = t % HW;
    int h = p / W, w = p % W;

    float g[5];
    {
        float s = 0.f;
        #pragma unroll
        for (int i = 0; i < 5; i++) {
            float c = (float)(i - 2);
            g[i] = expf(-(c * c) / 4.5f);
            s += g[i];
        }
        #pragma unroll
        for (int i = 0; i < 5; i++) g[i] /= s;
    }

    const float* sb = seg + (size_t)b * HW;
    float acc = 0.f;
    #pragma unroll
    for (int dy = -2; dy <= 2; dy++) {
        int hh = h + dy;
        if (hh < 0 || hh >= H) continue;
        float rowacc = 0.f;
        #pragma unroll
        for (int dx = -2; dx <= 2; dx++) {
            int ww = w + dx;
            if (ww < 0 || ww >= W) continue;
            rowacc += rintf(sb[hh * W + ww]) * g[dx + 2];
        }
        acc += rowacc * g[dy + 2];
    }
    cleaned[t] = rintf(acc);
}

// ---------------- Kernel 2: per-batch top-K + detect + sequential NMS --------
__global__ __launch_bounds__(256) void k_detect(const float* __restrict__ mscore,
                                                const float* __restrict__ mori,
                                                const float* __restrict__ mxo,
                                                const float* __restrict__ myo,
                                                const float* __restrict__ cleaned,
                                                float* __restrict__ out) {
    __shared__ unsigned long long s_key[HW];     // (enc(score)<<32) | (HW - i)
    __shared__ unsigned long long s_w[4];
    __shared__ float s_x[KC], s_y[KC], s_ang[KC], s_val[KC];
    __shared__ int   s_idx[KC];
    __shared__ int   s_keep[KC];

    const int b = blockIdx.x, tid = threadIdx.x;
    const int wave = tid >> 6;
    const int lane = tid & 63;

    for (int i = tid; i < HW; i += 256) {
        float v = mscore[(size_t)b * HW + i] * cleaned[(size_t)b * HW + i];
        s_key[i] = ((unsigned long long)enc_f(v) << 32) | (unsigned)(HW - i);
    }
    __syncthreads();

    // iterative top-K: max over packed key == (value desc, index asc)
    for (int k = 0; k < KC; k++) {
        unsigned long long best = 0ull;
        #pragma unroll
        for (int j = 0; j < HW / 256; j++) {
            unsigned long long key = s_key[j * 256 + tid];
            if (key > best) best = key;
        }
        #pragma unroll
        for (int off = 32; off > 0; off >>= 1) {
            unsigned long long o = __shfl_xor(best, off);
            if (o > best) best = o;
        }
        if (lane == 0) s_w[wave] = best;
        __syncthreads();
        if (tid == 0) {
            unsigned long long b0 = s_w[0];
            if (s_w[1] > b0) b0 = s_w[1];
            if (s_w[2] > b0) b0 = s_w[2];
            if (s_w[3] > b0) b0 = s_w[3];
            int idx = HW - (int)(b0 & 0xFFFFFFFFull);
            s_idx[k] = idx;
            s_val[k] = dec_f((unsigned)(b0 >> 32));
            s_key[idx] = 0ull;   // remove winner
        }
        __syncthreads();
    }

    // per-candidate channel argmaxes + mnt
    if (tid < KC) {
        int idx = s_idx[tid];
        int r = idx / W, c = idx % W;

        const float* pm = mori + (size_t)b * NCH * HW + idx;
        float best = pm[0]; int bj = 0;
        for (int j = 1; j < NCH; j++) {
            float v = pm[(size_t)j * HW];
            if (v > best) { best = v; bj = j; }
        }
        const float* px = mxo + (size_t)b * 8 * HW + idx;
        float bxv = px[0]; int xo = 0;
        #pragma unroll
        for (int j = 1; j < 8; j++) { float v = px[(size_t)j * HW]; if (v > bxv) { bxv = v; xo = j; } }
        const float* py = myo + (size_t)b * 8 * HW + idx;
        float byv = py[0]; int yo = 0;
        #pragma unroll
        for (int j = 1; j < 8; j++) { float v = py[(size_t)j * HW]; if (v > byv) { byv = v; yo = j; } }

        float ang = ((float)bj * 2.0f - 89.0f) * (float)(PI_F / 180.0);
        float x = (float)c * 8.0f + (float)xo;
        float y = (float)r * 8.0f + (float)yo;
        s_x[tid] = x; s_y[tid] = y; s_ang[tid] = ang;
        s_keep[tid] = (s_val[tid] > 0.1f) ? 1 : 0;

        float* m = out + OUT_MNT + ((size_t)b * KC + tid) * 4;
        m[0] = x; m[1] = y; m[2] = ang; m[3] = s_val[tid];
    }
    __syncthreads();

    // sequential NMS (reference semantics preserved literally)
    for (int i = 0; i < KC; i++) {
        if (s_keep[i]) {
            if (tid < KC && tid > i && s_keep[tid]) {
                float dx = s_x[i] - s_x[tid];
                float dy = s_y[i] - s_y[tid];
                float dist = sqrtf(dx * dx + dy * dy);
                float ad = fabsf(s_ang[i] - s_ang[tid]);
                float am = fminf(ad, 2.0f * (float)PI_F - ad);
                if (dist < 16.0f && am < (float)(PI_F / 6.0)) s_keep[tid] = 0;
            }
        }
        __syncthreads();
    }

    if (tid < KC)
        out[OUT_KEEP + (size_t)b * KC + tid] = s_keep[tid] ? 1.0f : 0.0f;
}

// ---------------- Kernel 3: orientation argmax over 90 channels (float4) -----
__global__ __launch_bounds__(256) void k_ori(const float* __restrict__ ori,
                                             float* __restrict__ ori_idx) {
    int t4 = blockIdx.x * 256 + threadIdx.x;          // BN*HW/4 threads
    if (t4 >= BN * HW / 4) return;
    int b = t4 / (HW / 4), p4 = t4 % (HW / 4);
    const float4* o = (const float4*)(ori + (size_t)b * NCH * HW) + p4;
    float4 bv = o[0];
    float bj0 = 0.f, bj1 = 0.f, bj2 = 0.f, bj3 = 0.f;
    for (int j = 1; j < NCH; j++) {
        float4 v = o[(size_t)j * (HW / 4)];
        if (v.x > bv.x) { bv.x = v.x; bj0 = (float)j; }
        if (v.y > bv.y) { bv.y = v.y; bj1 = (float)j; }
        if (v.z > bv.z) { bv.z = v.z; bj2 = (float)j; }
        if (v.w > bv.w) { bv.w = v.w; bj3 = (float)j; }
    }
    ((float4*)ori_idx)[t4] = make_float4(bj0, bj1, bj2, bj3);
}

// ---------------- Kernel 4a: per-block partial min/max (no atomics) ----------
__global__ __launch_bounds__(256) void k_minmax_part(const float* __restrict__ enh,
                                                     const float* __restrict__ cleaned,
                                                     float* __restrict__ pmin,
                                                     float* __restrict__ pmax) {
    const int b = blockIdx.y;
    const float4* e4 = (const float4*)(enh + (size_t)b * UHW);
    const float* cb = cleaned + (size_t)b * HW;

    float vmin = INFINITY, vmax = -INFINITY;
    for (int i = blockIdx.x * 256 + threadIdx.x; i < UHW / 4; i += MM_BLOCKS * 256) {
        float4 v = e4[i];
        int p = i * 4;
        int Y = p / UW, X = p % UW;                   // group of 4 stays in one x8 cell
        float c = cb[(Y >> 3) * W + (X >> 3)];
        float a = v.x * c, bb = v.y * c, cc = v.z * c, dd = v.w * c;
        vmin = fminf(vmin, fminf(fminf(a, bb), fminf(cc, dd)));
        vmax = fmaxf(vmax, fmaxf(fmaxf(a, bb), fmaxf(cc, dd)));
    }

    __shared__ float smin[4], smax[4];
    #pragma unroll
    for (int off = 32; off > 0; off >>= 1) {
        vmin = fminf(vmin, __shfl_xor(vmin, off));
        vmax = fmaxf(vmax, __shfl_xor(vmax, off));
    }
    int wave = threadIdx.x >> 6, lane = threadIdx.x & 63;
    if (lane == 0) { smin[wave] = vmin; smax[wave] = vmax; }
    __syncthreads();
    if (threadIdx.x == 0) {
        float m0 = fminf(fminf(smin[0], smin[1]), fminf(smin[2], smin[3]));
        float m1 = fmaxf(fmaxf(smax[0], smax[1]), fmaxf(smax[2], smax[3]));
        pmin[b * MM_BLOCKS + blockIdx.x] = m0;
        pmax[b * MM_BLOCKS + blockIdx.x] = m1;
    }
}

// ---------------- Kernel 4b: reduce partials -> per-image min/max ------------
__global__ __launch_bounds__(64) void k_minmax_final(const float* __restrict__ pmin,
                                                     const float* __restrict__ pmax,
                                                     float* __restrict__ mm) {
    const int b = blockIdx.x;
    float vmin = pmin[b * MM_BLOCKS + threadIdx.x];
    float vmax = pmax[b * MM_BLOCKS + threadIdx.x];
    #pragma unroll
    for (int off = 32; off > 0; off >>= 1) {
        vmin = fminf(vmin, __shfl_xor(vmin, off));
        vmax = fmaxf(vmax, __shfl_xor(vmax, off));
    }
    if (threadIdx.x == 0) { mm[2 * b] = vmin; mm[2 * b + 1] = vmax; }
}

// ---------------- Kernel 5: fused upsample + normalize + writes (float4) -----
__global__ __launch_bounds__(256) void k_final(const float* __restrict__ enh,
                                               const float* __restrict__ cleaned,
                                               const float* __restrict__ ori_idx,
                                               const float* __restrict__ mm,
                                               float* __restrict__ out) {
    int t4 = blockIdx.x * 256 + threadIdx.x;          // BN*UHW/4 threads
    int b = t4 / (UHW / 4), p4 = t4 % (UHW / 4);
    int p = p4 * 4;
    int Y = p / UW, X = p % UW;                       // group of 4 in one x8 cell
    int cidx = b * HW + (Y >> 3) * W + (X >> 3);
    float c  = cleaned[cidx];
    float oi = ori_idx[cidx];
    float emin = mm[2 * b];
    float emax = mm[2 * b + 1];
    float inv = 255.0f / (emax - emin + 1e-8f);

    float4 e = ((const float4*)enh)[t4];
    float4 ev;
    ev.x = (e.x * c - emin) * inv;
    ev.y = (e.y * c - emin) * inv;
    ev.z = (e.z * c - emin) * inv;
    ev.w = (e.w * c - emin) * inv;

    float cv = c * 255.0f;
    float ov = (oi * 2.0f - 89.0f) * (float)(PI_F / 180.0) * c;

    ((float4*)(out + OUT_ENH))[t4]   = ev;
    ((float4*)(out + OUT_CLEAN))[t4] = make_float4(cv, cv, cv, cv);
    ((float4*)(out + OUT_ORI))[t4]   = make_float4(ov, ov, ov, ov);
}

extern "C" void kernel_launch(void* const* d_in, const int* in_sizes, int n_in,
                              void* d_out, int out_size, void* d_ws, size_t ws_size,
                              hipStream_t stream) {
    const float* seg    = (const float*)d_in[0];
    const float* mscore = (const float*)d_in[1];
    const float* mori   = (const float*)d_in[2];
    const float* mxo    = (const float*)d_in[3];
    const float* myo    = (const float*)d_in[4];
    const float* ori    = (const float*)d_in[5];
    const float* enh    = (const float*)d_in[6];
    float* out = (float*)d_out;

    // workspace layout
    float* cleaned = (float*)d_ws;                         // BN*HW
    float* ori_idx = cleaned + (size_t)BN * HW;            // BN*HW
    float* pmin    = ori_idx + (size_t)BN * HW;            // BN*MM_BLOCKS
    float* pmax    = pmin + (size_t)BN * MM_BLOCKS;        // BN*MM_BLOCKS
    float* mm      = pmax + (size_t)BN * MM_BLOCKS;        // 2*BN

    const int nSmall = (BN * HW + 255) / 256;              // 800
    const int nOri   = (BN * HW / 4 + 255) / 256;          // 200
    const int nBig4  = (BN * UHW / 4) / 256;               // 12800

    k_cleaned<<<nSmall, 256, 0, stream>>>(seg, cleaned);
    k_detect<<<BN, 256, 0, stream>>>(mscore, mori, mxo, myo, cleaned, out);
    k_ori<<<nOri, 256, 0, stream>>>(ori, ori_idx);
    k_minmax_part<<<dim3(MM_BLOCKS, BN), 256, 0, stream>>>(enh, cleaned, pmin, pmax);
    k_minmax_final<<<BN, 64, 0, stream>>>(pmin, pmax, mm);
    k_final<<<nBig4, 256, 0, stream>>>(enh, cleaned, ori_idx, mm, out);
}

// Round 3
// 174.689 us; speedup vs baseline: 5.7824x; 1.2973x over previous
//
#include <hip/hip_runtime.h>
#include <math.h>

#define BN  32
#define H   80
#define W   80
#define HW  6400
#define KC  100
#define NCH 90
#define UW  640
#define UHW 409600   // 640*640

static constexpr size_t OUT_MNT   = 0;
static constexpr size_t OUT_KEEP  = (size_t)BN * KC * 4;          // 12800
static constexpr size_t OUT_ENH   = OUT_KEEP + (size_t)BN * KC;   // 16000
static constexpr size_t OUT_CLEAN = OUT_ENH + (size_t)BN * UHW;   // 13123200
static constexpr size_t OUT_ORI   = OUT_CLEAN + (size_t)BN * UHW; // 26230400

#define PI_F 3.14159265358979323846
#define MM_BLOCKS 64   // partial-reduction blocks per batch image

// ---------------- float <-> order-preserving uint ----------------
__device__ __forceinline__ unsigned enc_f(float f) {
    unsigned u = __float_as_uint(f);
    return (u & 0x80000000u) ? ~u : (u | 0x80000000u);
}
__device__ __forceinline__ float dec_f(unsigned k) {
    return (k & 0x80000000u) ? __uint_as_float(k ^ 0x80000000u) : __uint_as_float(~k);
}
// 64-bit xor-shuffle (2 x 32-bit lane shuffles, bit-exact)
__device__ __forceinline__ unsigned long long shflx(unsigned long long v, int off) {
    unsigned hi = (unsigned)__shfl_xor((int)(unsigned)(v >> 32), off);
    unsigned lo = (unsigned)__shfl_xor((int)(unsigned)(v & 0xffffffffull), off);
    return ((unsigned long long)hi << 32) | lo;
}

// ---------------- Kernel 1: cleaned mask (round -> blur5x5 -> round) ---------
__global__ __launch_bounds__(256) void k_cleaned(const float* __restrict__ seg,
                                                 float* __restrict__ cleaned) {
    int t = blockIdx.x * 256 + threadIdx.x;
    if (t >= BN * HW) return;
    int b = t / HW, p = t % HW;
    int h = p / W, w = p % W;

    float g[5];
    {
        float s = 0.f;
        #pragma unroll
        for (int i = 0; i < 5; i++) {
            float c = (float)(i - 2);
            g[i] = expf(-(c * c) / 4.5f);
            s += g[i];
        }
        #pragma unroll
        for (int i = 0; i < 5; i++) g[i] /= s;
    }

    const float* sb = seg + (size_t)b * HW;
    float acc = 0.f;
    #pragma unroll
    for (int dy = -2; dy <= 2; dy++) {
        int hh = h + dy;
        if (hh < 0 || hh >= H) continue;
        float rowacc = 0.f;
        #pragma unroll
        for (int dx = -2; dx <= 2; dx++) {
            int ww = w + dx;
            if (ww < 0 || ww >= W) continue;
            rowacc += rintf(sb[hh * W + ww]) * g[dx + 2];
        }
        acc += rowacc * g[dy + 2];
    }
    cleaned[t] = rintf(acc);
}

// ---------------- rank-based parallel merge of 8 sorted (desc) lists ---------
__device__ __forceinline__ void rank_merge(unsigned long long (*s_list)[KC],
                                           unsigned long long* s_sel,
                                           int C, int tid) {
    int total = 8 * C;
    for (int e = tid; e < total; e += 512) {
        int w = e / C, p = e % C;
        unsigned long long kkey = s_list[w][p];
        int rank = p;
        #pragma unroll
        for (int w2 = 0; w2 < 8; w2++) {
            if (w2 == w) continue;
            int lo = 0, hi = C;   // count of entries strictly greater (keys distinct)
            while (lo < hi) {
                int mid = (lo + hi) >> 1;
                if (s_list[w2][mid] > kkey) lo = mid + 1; else hi = mid;
            }
            rank += lo;
        }
        if (rank < KC) s_sel[rank] = kkey;
    }
}

// ---------------- Kernel 2a: per-batch exact top-K (register-cached) ---------
__global__ __launch_bounds__(512) void k_topk(const float* __restrict__ mscore,
                                              const float* __restrict__ cleaned,
                                              int* __restrict__ ws_idx,
                                              float* __restrict__ ws_val) {
    __shared__ unsigned long long s_list[8][KC];
    __shared__ unsigned long long s_sel[KC];
    __shared__ unsigned long long s_lm[8];
    __shared__ int s_ok;

    const int b = blockIdx.x, tid = threadIdx.x;
    const int wave = tid >> 6, lane = tid & 63;

    // each wave owns 800 elements; 13 keys/lane in registers
    unsigned long long key[13];
    const float* ms = mscore + (size_t)b * HW;
    const float* cl = cleaned + (size_t)b * HW;
    #pragma unroll
    for (int j = 0; j < 13; j++) {
        int il = j * 64 + lane;
        if (il < 800) {
            int i = wave * 800 + il;
            float v = ms[i] * cl[i];
            key[j] = ((unsigned long long)enc_f(v) << 32) | (unsigned)(HW - i);
        } else {
            key[j] = 0ull;   // real keys are >= 2^63 (score >= 0)
        }
    }
    unsigned long long lmax = key[0];
    #pragma unroll
    for (int j = 1; j < 13; j++) if (key[j] > lmax) lmax = key[j];

    auto extract = [&](int k) {
        unsigned long long gm = lmax;
        #pragma unroll
        for (int off = 32; off > 0; off >>= 1) {
            unsigned long long o = shflx(gm, off);
            if (o > gm) gm = o;
        }
        if (lane == 0) s_list[wave][k] = gm;
        if (lmax == gm) {           // unique owner lane (keys distinct)
            #pragma unroll
            for (int j = 0; j < 13; j++) if (key[j] == gm) key[j] = 0ull;
            unsigned long long m = key[0];
            #pragma unroll
            for (int j = 1; j < 13; j++) if (key[j] > m) m = key[j];
            lmax = m;
        }
    };

    // phase 1: 32 extractions per wave (expected sufficient for global top-100)
    for (int k = 0; k < 32; k++) extract(k);
    if (lane == 0) s_lm[wave] = lmax;
    __syncthreads();

    rank_merge(s_list, s_sel, 32, tid);
    __syncthreads();
    if (tid == 0) {
        unsigned long long v100 = s_sel[KC - 1];
        int ok = 1;
        #pragma unroll
        for (int w = 0; w < 8; w++) ok &= (s_lm[w] < v100) ? 1 : 0;
        s_ok = ok;   // every wave's remaining max below merged 100th -> exact
    }
    __syncthreads();

    if (!s_ok) {   // fallback (provably correct): full 100 per wave
        for (int k = 32; k < KC; k++) extract(k);
        __syncthreads();
        rank_merge(s_list, s_sel, KC, tid);
        __syncthreads();
    }

    if (tid < KC) {
        unsigned long long e = s_sel[tid];
        ws_idx[(size_t)b * KC + tid] = HW - (int)(e & 0xffffffffull);
        ws_val[(size_t)b * KC + tid] = dec_f((unsigned)(e >> 32));
    }
}

// ---------------- Kernel 2b: one wave per candidate: channel argmax gather ---
__global__ __launch_bounds__(256) void k_gather(const float* __restrict__ mori,
                                                const float* __restrict__ mxo,
                                                const float* __restrict__ myo,
                                                const int* __restrict__ ws_idx,
                                                const float* __restrict__ ws_val,
                                                float* __restrict__ out) {
    int wid = blockIdx.x * 4 + (threadIdx.x >> 6);
    int lane = threadIdx.x & 63;
    int b = wid / KC, k = wid % KC;
    int idx = ws_idx[(size_t)b * KC + k];

    // orientation argmax over 90 channels: lane ch + ch+64 (lane<26)
    const float* pm = mori + (size_t)b * NCH * HW + idx;
    unsigned long long kk =
        ((unsigned long long)enc_f(pm[(size_t)lane * HW]) << 32) | (unsigned)(127 - lane);
    if (lane < NCH - 64) {
        unsigned long long k1 =
            ((unsigned long long)enc_f(pm[(size_t)(64 + lane) * HW]) << 32) | (unsigned)(127 - (64 + lane));
        if (k1 > kk) kk = k1;
    }
    // x/y offset argmax over 8 channels on lanes 32..39 / 40..47
    unsigned long long kx = 0ull, ky = 0ull;
    if (lane >= 32 && lane < 40)
        kx = ((unsigned long long)enc_f(mxo[((size_t)b * 8 + (lane - 32)) * HW + idx]) << 32)
             | (unsigned)(15 - (lane - 32));
    if (lane >= 40 && lane < 48)
        ky = ((unsigned long long)enc_f(myo[((size_t)b * 8 + (lane - 40)) * HW + idx]) << 32)
             | (unsigned)(15 - (lane - 40));

    #pragma unroll
    for (int off = 32; off > 0; off >>= 1) {
        unsigned long long o;
        o = shflx(kk, off); if (o > kk) kk = o;
        o = shflx(kx, off); if (o > kx) kx = o;
        o = shflx(ky, off); if (o > ky) ky = o;
    }

    if (lane == 0) {
        int ch = 127 - (int)(kk & 0xffffffffull);
        int xo = 15  - (int)(kx & 0xffffffffull);
        int yo = 15  - (int)(ky & 0xffffffffull);
        int r = idx / W, c = idx % W;
        float4 m;
        m.x = (float)c * 8.0f + (float)xo;
        m.y = (float)r * 8.0f + (float)yo;
        m.z = ((float)ch * 2.0f - 89.0f) * (float)(PI_F / 180.0);
        m.w = ws_val[(size_t)b * KC + k];
        ((float4*)(out + OUT_MNT))[(size_t)b * KC + k] = m;
    }
}

// ---------------- Kernel 2c: sequential NMS, one wave per batch, registers ---
__global__ __launch_bounds__(64) void k_nms(float* __restrict__ out) {
    const int b = blockIdx.x, l = threadIdx.x;
    const float4* mnt = (const float4*)(out + OUT_MNT) + (size_t)b * KC;
    float4 m0 = mnt[l];                       // candidate l
    bool has1 = (l + 64) < KC;                // candidate l+64 (l<36)
    float4 m1 = has1 ? mnt[l + 64] : make_float4(0.f, 0.f, 0.f, -1.f);
    int keep0 = (m0.w > 0.1f) ? 1 : 0;
    int keep1 = (has1 && m1.w > 0.1f) ? 1 : 0;

    for (int i = 0; i < KC; i++) {
        bool hi = i >= 64;
        int src = i & 63;
        float xi = __shfl(hi ? m1.x : m0.x, src);
        float yi = __shfl(hi ? m1.y : m0.y, src);
        float ai = __shfl(hi ? m1.z : m0.z, src);
        int   ki = __shfl(hi ? keep1 : keep0, src);
        if (ki) {
            if (keep0 && l > i) {
                float dx = xi - m0.x, dy = yi - m0.y;
                float dist = sqrtf(dx * dx + dy * dy);
                float ad = fabsf(ai - m0.z);
                float am = fminf(ad, (float)(2.0 * PI_F) - ad);
                if (dist < 16.0f && am < (float)(PI_F / 6.0)) keep0 = 0;
            }
            if (keep1 && (l + 64) > i) {
                float dx = xi - m1.x, dy = yi - m1.y;
                float dist = sqrtf(dx * dx + dy * dy);
                float ad = fabsf(ai - m1.z);
                float am = fminf(ad, (float)(2.0 * PI_F) - ad);
                if (dist < 16.0f && am < (float)(PI_F / 6.0)) keep1 = 0;
            }
        }
    }
    out[OUT_KEEP + (size_t)b * KC + l] = (float)keep0;
    if (has1) out[OUT_KEEP + (size_t)b * KC + 64 + l] = (float)keep1;
}

// ---------------- Kernel 3: orientation argmax over 90 channels (float4) -----
__global__ __launch_bounds__(256) void k_ori(const float* __restrict__ ori,
                                             float* __restrict__ ori_idx) {
    int t4 = blockIdx.x * 256 + threadIdx.x;          // BN*HW/4 threads
    if (t4 >= BN * HW / 4) return;
    int b = t4 / (HW / 4), p4 = t4 % (HW / 4);
    const float4* o = (const float4*)(ori + (size_t)b * NCH * HW) + p4;
    float4 bv = o[0];
    float bj0 = 0.f, bj1 = 0.f, bj2 = 0.f, bj3 = 0.f;
    for (int j = 1; j < NCH; j++) {
        float4 v = o[(size_t)j * (HW / 4)];
        if (v.x > bv.x) { bv.x = v.x; bj0 = (float)j; }
        if (v.y > bv.y) { bv.y = v.y; bj1 = (float)j; }
        if (v.z > bv.z) { bv.z = v.z; bj2 = (float)j; }
        if (v.w > bv.w) { bv.w = v.w; bj3 = (float)j; }
    }
    ((float4*)ori_idx)[t4] = make_float4(bj0, bj1, bj2, bj3);
}

// ---------------- Kernel 4a: per-block partial min/max (no atomics) ----------
__global__ __launch_bounds__(256) void k_minmax_part(const float* __restrict__ enh,
                                                     const float* __restrict__ cleaned,
                                                     float* __restrict__ pmin,
                                                     float* __restrict__ pmax) {
    const int b = blockIdx.y;
    const float4* e4 = (const float4*)(enh + (size_t)b * UHW);
    const float* cb = cleaned + (size_t)b * HW;

    float vmin = INFINITY, vmax = -INFINITY;
    for (int i = blockIdx.x * 256 + threadIdx.x; i < UHW / 4; i += MM_BLOCKS * 256) {
        float4 v = e4[i];
        int p = i * 4;
        int Y = p / UW, X = p % UW;                   // group of 4 stays in one x8 cell
        float c = cb[(Y >> 3) * W + (X >> 3)];
        float a = v.x * c, bb = v.y * c, cc = v.z * c, dd = v.w * c;
        vmin = fminf(vmin, fminf(fminf(a, bb), fminf(cc, dd)));
        vmax = fmaxf(vmax, fmaxf(fmaxf(a, bb), fmaxf(cc, dd)));
    }

    __shared__ float smin[4], smax[4];
    #pragma unroll
    for (int off = 32; off > 0; off >>= 1) {
        vmin = fminf(vmin, __shfl_xor(vmin, off));
        vmax = fmaxf(vmax, __shfl_xor(vmax, off));
    }
    int wave = threadIdx.x >> 6, lane = threadIdx.x & 63;
    if (lane == 0) { smin[wave] = vmin; smax[wave] = vmax; }
    __syncthreads();
    if (threadIdx.x == 0) {
        float m0 = fminf(fminf(smin[0], smin[1]), fminf(smin[2], smin[3]));
        float m1 = fmaxf(fmaxf(smax[0], smax[1]), fmaxf(smax[2], smax[3]));
        pmin[b * MM_BLOCKS + blockIdx.x] = m0;
        pmax[b * MM_BLOCKS + blockIdx.x] = m1;
    }
}

// ---------------- Kernel 4b: reduce partials -> per-image min/max ------------
__global__ __launch_bounds__(64) void k_minmax_final(const float* __restrict__ pmin,
                                                     const float* __restrict__ pmax,
                                                     float* __restrict__ mm) {
    const int b = blockIdx.x;
    float vmin = pmin[b * MM_BLOCKS + threadIdx.x];
    float vmax = pmax[b * MM_BLOCKS + threadIdx.x];
    #pragma unroll
    for (int off = 32; off > 0; off >>= 1) {
        vmin = fminf(vmin, __shfl_xor(vmin, off));
        vmax = fmaxf(vmax, __shfl_xor(vmax, off));
    }
    if (threadIdx.x == 0) { mm[2 * b] = vmin; mm[2 * b + 1] = vmax; }
}

// ---------------- Kernel 5: fused upsample + normalize + writes (float4) -----
__global__ __launch_bounds__(256) void k_final(const float* __restrict__ enh,
                                               const float* __restrict__ cleaned,
                                               const float* __restrict__ ori_idx,
                                               const float* __restrict__ mm,
                                               float* __restrict__ out) {
    int t4 = blockIdx.x * 256 + threadIdx.x;          // BN*UHW/4 threads
    int b = t4 / (UHW / 4), p4 = t4 % (UHW / 4);
    int p = p4 * 4;
    int Y = p / UW, X = p % UW;                       // group of 4 in one x8 cell
    int cidx = b * HW + (Y >> 3) * W + (X >> 3);
    float c  = cleaned[cidx];
    float oi = ori_idx[cidx];
    float emin = mm[2 * b];
    float emax = mm[2 * b + 1];
    float inv = 255.0f / (emax - emin + 1e-8f);

    float4 e = ((const float4*)enh)[t4];
    float4 ev;
    ev.x = (e.x * c - emin) * inv;
    ev.y = (e.y * c - emin) * inv;
    ev.z = (e.z * c - emin) * inv;
    ev.w = (e.w * c - emin) * inv;

    float cv = c * 255.0f;
    float ov = (oi * 2.0f - 89.0f) * (float)(PI_F / 180.0) * c;

    ((float4*)(out + OUT_ENH))[t4]   = ev;
    ((float4*)(out + OUT_CLEAN))[t4] = make_float4(cv, cv, cv, cv);
    ((float4*)(out + OUT_ORI))[t4]   = make_float4(ov, ov, ov, ov);
}

extern "C" void kernel_launch(void* const* d_in, const int* in_sizes, int n_in,
                              void* d_out, int out_size, void* d_ws, size_t ws_size,
                              hipStream_t stream) {
    const float* seg    = (const float*)d_in[0];
    const float* mscore = (const float*)d_in[1];
    const float* mori   = (const float*)d_in[2];
    const float* mxo    = (const float*)d_in[3];
    const float* myo    = (const float*)d_in[4];
    const float* ori    = (const float*)d_in[5];
    const float* enh    = (const float*)d_in[6];
    float* out = (float*)d_out;

    // workspace layout
    float* cleaned = (float*)d_ws;                         // BN*HW
    float* ori_idx = cleaned + (size_t)BN * HW;            // BN*HW
    float* pmin    = ori_idx + (size_t)BN * HW;            // BN*MM_BLOCKS
    float* pmax    = pmin + (size_t)BN * MM_BLOCKS;        // BN*MM_BLOCKS
    float* mm      = pmax + (size_t)BN * MM_BLOCKS;        // 2*BN
    int*   ws_idx  = (int*)(mm + 2 * BN);                  // BN*KC
    float* ws_val  = (float*)(ws_idx + (size_t)BN * KC);   // BN*KC

    const int nSmall = (BN * HW + 255) / 256;              // 800
    const int nOri   = (BN * HW / 4 + 255) / 256;          // 200
    const int nBig4  = (BN * UHW / 4) / 256;               // 12800

    k_cleaned<<<nSmall, 256, 0, stream>>>(seg, cleaned);
    k_topk<<<BN, 512, 0, stream>>>(mscore, cleaned, ws_idx, ws_val);
    k_gather<<<(BN * KC) / 4, 256, 0, stream>>>(mori, mxo, myo, ws_idx, ws_val, out);
    k_nms<<<BN, 64, 0, stream>>>(out);
    k_ori<<<nOri, 256, 0, stream>>>(ori, ori_idx);
    k_minmax_part<<<dim3(MM_BLOCKS, BN), 256, 0, stream>>>(enh, cleaned, pmin, pmax);
    k_minmax_final<<<BN, 64, 0, stream>>>(pmin, pmax, mm);
    k_final<<<nBig4, 256, 0, stream>>>(enh, cleaned, ori_idx, mm, out);
}